// Round 5
// baseline (481.975 us; speedup 1.0000x reference)
//
#include <hip/hip_runtime.h>
#include <hip/hip_fp16.h>

typedef _Float16 f16;
typedef _Float16 f16x4 __attribute__((ext_vector_type(4)));
typedef _Float16 f16x8 __attribute__((ext_vector_type(8)));
typedef float f32x4 __attribute__((ext_vector_type(4)));

// B=2, T=2048, D=2048, NH=16, HD=128, Q_LAT=1024, KV_LAT=512
#define BT 4096
#define DMODEL 2048

__device__ __forceinline__ void gld16(const f16* g, f16* l) {
    __builtin_amdgcn_global_load_lds((const __attribute__((address_space(1))) void*)g,
                                     (__attribute__((address_space(3))) void*)l, 16, 0, 0);
}

// ---------------------------------------------------------------- fused fp32 -> fp16 (7 tensors, 1 launch)
struct Cvt7 {
    const float* s[7];
    f16* d[7];
    int off4[8];  // cumulative float4 counts
};
__global__ __launch_bounds__(256) void k_cvt7(Cvt7 c) {
    int i = blockIdx.x * 256 + threadIdx.x;
    if (i >= c.off4[7]) return;
    int seg = 0;
#pragma unroll
    for (int k = 1; k < 7; ++k) seg += (i >= c.off4[k]);
    int j = i - c.off4[seg];
    float4 v = ((const float4*)c.s[seg])[j];
    f16x4 h;
    h[0] = (f16)v.x; h[1] = (f16)v.y; h[2] = (f16)v.z; h[3] = (f16)v.w;
    ((f16x4*)c.d[seg])[j] = h;
}

// ---------------------------------------------------------------- pipelined GEMM (r3-proven loop)
// C[M,N] = A[M,K] @ B[N,K]^T. Tile 128(M) x 256(N), BK=64 as two 32-wide kc-halves.
// 512 threads = 8 waves (2M x 4N), per-wave 64x64 output. LDS 96KB -> 1 block/CU.
// NEW (r5): chunked column-major XCD swizzle (T1, m204-bijective). gridDim.y==32 always.
// XCD j owns contiguous COLUMN-major chunks -> its B-panel(s) (0.25-1MB) stay L2-resident
// across the 32 m-blocks that share them (was: panels scattered over 8 L2s, ~9MB/XCD thrash).
// MODE 0: plain -> C0 (CT). MODE 1: dual split at nsplit. MODE 2: k + V^T direct store.
template <int MODE, typename CT>
__global__ __launch_bounds__(512, 2) void k_gemm8(const f16* __restrict__ A,
                                                  const f16* __restrict__ B0,
                                                  const f16* __restrict__ B1,
                                                  CT* __restrict__ C0,
                                                  f16* __restrict__ C1,
                                                  int K, int nsplit, int ld0, int ld1) {
    __shared__ __align__(16) f16 lds[49152];  // 96 KB
    const int tid = threadIdx.x;
    const int w = tid >> 6, l = tid & 63;
    const int wm = w >> 2, wn = w & 3;          // 2M x 4N waves
    const int quad = l >> 4, ln = l & 15;
    // --- XCD swizzle: hw linear id (x fastest), XCD = lin%8; give each XCD a
    // contiguous run of column-major (n-panel-major) chunks. nwg % 8 == 0 for all grids.
    const int gx = gridDim.x;
    const int lin = blockIdx.y * gx + blockIdx.x;
    const int nwg = gx << 5;                    // gridDim.y == 32
    const int chunk = (lin & 7) * (nwg >> 3) + (lin >> 3);
    const int m0 = (chunk & 31) * 128, n0 = (chunk >> 5) * 256;

    const f16* Bp;
    if constexpr (MODE == 0) {
        Bp = B0 + (size_t)n0 * K;
    } else if constexpr (MODE == 1) {
        Bp = (n0 < nsplit) ? B0 + (size_t)n0 * K : B1 + (size_t)(n0 - nsplit) * K;
    } else {
        Bp = (n0 < 2048) ? B0 + (size_t)n0 * K : B1 + (size_t)(n0 - 2048) * K;
    }

    // staging: A half = 128 rows x 32 k (1 round of 512x16B), B half = 256 x 32 (2 rounds)
    const f16* ag  = A + (size_t)(m0 + w * 16 + (l >> 2)) * K + (l & 3) * 8;
    const f16* bg0 = Bp + (size_t)(w * 16 + (l >> 2)) * K + (l & 3) * 8;
    const f16* bg1 = bg0 + (size_t)128 * K;
    f16* al = &lds[w * 512];         // + slot offset; lane*16B appended by HW
    f16* bl = &lds[4096 + w * 512];

#define STAGE8(buf_, kc_, t_)                          \
    {                                                  \
        const int off_ = ((buf_) * 2 + (kc_)) * 12288; \
        const int g_ = (t_) * 64 + (kc_) * 32;         \
        gld16(ag + g_, al + off_);                     \
        gld16(bg0 + g_, bl + off_);                    \
        gld16(bg1 + g_, bl + off_ + 4096);             \
    }

    f32x4 acc[4][4];
#pragma unroll
    for (int i = 0; i < 4; ++i)
#pragma unroll
        for (int j = 0; j < 4; ++j)
#pragma unroll
            for (int r = 0; r < 4; ++r) acc[i][j][r] = 0.f;

    const int nt = K >> 6;
    // prologue: tile 0 complete + tile 1 early half; vmcnt(3) -> tile 0 landed
    STAGE8(0, 0, 0);
    STAGE8(0, 1, 0);
    STAGE8(1, 0, 1);
    asm volatile("s_waitcnt vmcnt(3)" ::: "memory");
    __builtin_amdgcn_s_barrier();
    asm volatile("s_waitcnt lgkmcnt(0)" ::: "memory");

    for (int t = 0; t < nt; ++t) {
        const int buf = t & 1;
#pragma unroll
        for (int kc = 0; kc < 2; ++kc) {
            const f16* Ah = &lds[(buf * 2 + kc) * 12288];
            const f16* Bh = Ah + 4096;
            f16x8 a[4], b[4];
#pragma unroll
            for (int i = 0; i < 4; ++i)
                a[i] = *(const f16x8*)&Ah[(wm * 64 + i * 16 + ln) * 32 + quad * 8];
#pragma unroll
            for (int j = 0; j < 4; ++j)
                b[j] = *(const f16x8*)&Bh[(wn * 64 + j * 16 + ln) * 32 + quad * 8];
            if (kc == 0) {
                if (t + 1 < nt) STAGE8(buf ^ 1, 1, t + 1);  // late half of next tile
            } else {
                if (t + 2 < nt) STAGE8(buf, 0, t + 2);      // early half of tile+2 (kc0 just freed)
            }
            __builtin_amdgcn_s_barrier();
            asm volatile("s_waitcnt lgkmcnt(0)" ::: "memory");  // own frag reads done (compiler fence)
            __builtin_amdgcn_s_setprio(1);
#pragma unroll
            for (int i = 0; i < 4; ++i)
#pragma unroll
                for (int j = 0; j < 4; ++j)
                    acc[i][j] = __builtin_amdgcn_mfma_f32_16x16x32_f16(a[i], b[j], acc[i][j], 0, 0, 0);
            __builtin_amdgcn_s_setprio(0);
            if (kc == 1 && t + 1 < nt) {
                if (t + 2 < nt) asm volatile("s_waitcnt vmcnt(3)" ::: "memory");
                else            asm volatile("s_waitcnt vmcnt(0)" ::: "memory");
            }
            __builtin_amdgcn_s_barrier();
        }
    }
#undef STAGE8

    // ---------------- epilogue
    if constexpr (MODE == 2) {
        if (n0 >= 2048) {  // V^T: vt[(b*2048+d)*2048 + t], direct from acc (4 consecutive t per lane)
            const int d0 = n0 - 2048;
            const int bb = m0 >> 11, tb = m0 & 2047;
#pragma unroll
            for (int i = 0; i < 4; ++i)
#pragma unroll
                for (int j = 0; j < 4; ++j) {
                    f16x4 v;
#pragma unroll
                    for (int r = 0; r < 4; ++r) v[r] = (f16)acc[i][j][r];
                    *(f16x4*)&C1[((size_t)(bb * 2048 + d0 + wn * 64 + j * 16 + ln)) * 2048 +
                                 tb + wm * 64 + i * 16 + quad * 4] = v;
                }
            return;
        }
    }

    CT* Cd; int ldc; int cb;
    if constexpr (MODE == 0) {
        Cd = C0; ldc = ld0; cb = n0;
    } else if constexpr (MODE == 1) {
        if (n0 < nsplit) { Cd = C0; ldc = ld0; cb = n0; }
        else             { Cd = (CT*)C1; ldc = ld1; cb = n0 - nsplit; }
    } else {
        Cd = C0; ldc = 2048; cb = n0;
    }

    const int p = (wm ? 16 : 0) + quad * 4;
    if constexpr (sizeof(CT) == 2) {
        f16* Cs = (f16*)lds;  // [32][264]
#pragma unroll
        for (int i = 0; i < 4; ++i) {
            __syncthreads();
#pragma unroll
            for (int j = 0; j < 4; ++j)
#pragma unroll
                for (int r = 0; r < 4; ++r)
                    Cs[(p + r) * 264 + wn * 64 + j * 16 + ln] = (f16)acc[i][j][r];
            __syncthreads();
#pragma unroll
            for (int rr = 0; rr < 2; ++rr) {
                int idx = rr * 512 + tid;
                int row = idx >> 5, c8 = idx & 31;
                int rg = m0 + i * 16 + (row & 15) + ((row & 16) ? 64 : 0);
                *(f16x8*)&Cd[(size_t)rg * ldc + cb + c8 * 8] = *(const f16x8*)&Cs[row * 264 + c8 * 8];
            }
        }
    } else {
        float* Cs = (float*)lds;  // [32][260]
#pragma unroll
        for (int i = 0; i < 4; ++i) {
            __syncthreads();
#pragma unroll
            for (int j = 0; j < 4; ++j)
#pragma unroll
                for (int r = 0; r < 4; ++r)
                    Cs[(p + r) * 260 + wn * 64 + j * 16 + ln] = acc[i][j][r];
            __syncthreads();
#pragma unroll
            for (int rr = 0; rr < 4; ++rr) {
                int idx = rr * 512 + tid;
                int row = idx >> 6, c4 = idx & 63;
                int rg = m0 + i * 16 + (row & 15) + ((row & 16) ? 64 : 0);
                *(float4*)&Cd[(size_t)rg * ldc + cb + c4 * 4] = *(const float4*)&Cs[row * 260 + c4 * 4];
            }
        }
    }
}

// ---------------------------------------------------------------- RMSNorm + RoPE (in place)
__global__ __launch_bounds__(256) void k_norm_rope(f16* __restrict__ q, f16* __restrict__ k,
                                                   const float* __restrict__ qw,
                                                   const float* __restrict__ kw) {
    const int gw = blockIdx.x * 4 + (threadIdx.x >> 6);
    const int l = threadIdx.x & 63;
    const int which = gw >> 16;
    const int rh = gw & 65535;
    const int row = rh >> 4, h = rh & 15;
    f16* p = which ? k : q;
    const float* wp = which ? kw : qw;
    const float scale = which ? 1.0f : 0.08838834764831843f;  // 1/sqrt(128) folded into q
    const size_t base = (size_t)row * DMODEL + h * 128;
    float xa = (float)p[base + l];
    float xb = (float)p[base + 64 + l];
    float ss = xa * xa + xb * xb;
#pragma unroll
    for (int off = 32; off > 0; off >>= 1) ss += __shfl_xor(ss, off);
    const float rms = rsqrtf(ss * (1.0f / 128.0f) + 1e-6f);
    const float na = xa * rms * wp[l];
    const float nb = xb * rms * wp[64 + l];
    const int t = row & 2047;
    const float freq = __expf((float)l * -0.1439115683121279f);  // ln(10000)/64
    const float ang = (float)t * freq;
    const float c = cosf(ang), s = sinf(ang);
    p[base + l]      = (f16)((na * c - nb * s) * scale);
    p[base + 64 + l] = (f16)((nb * c + na * s) * scale);
}

// ---------------------------------------------------------------- flash attention, causal, BM=64 BN=64
// S^T trick: S^T = K·Q^T so P lands in-register in 16x16x16 A-operand layout.
// r5 changes:
//  * Kl/Vl XOR-swizzled (byte ^= (row&7)<<4, same involution both sides) instead of
//    padded rows -> LDS 35.8KB -> 32KB exactly -> 5 blocks/CU (launch_bounds(256,5)).
//    All 1024 blocks resident from t=0 -> causal-tail self-balances (was 3/CU, 768
//    resident, Occupancy 28%). Bank-conflict floor unchanged by analysis.
//  * XCD swizzle: all 32 mt-blocks of one (h,b) share one XCD -> KV (1MB) L2-resident.
// T13 defer-max kept.
__global__ __launch_bounds__(256, 5) void k_flash(const f16* __restrict__ Q, const f16* __restrict__ K,
                                                  const f16* __restrict__ Vt, f16* __restrict__ O) {
    __shared__ f16 Kl[64 * 128];   // [t_k][d], col16 ^= row&7
    __shared__ f16 Vl[128 * 64];   // [d][t_k], col16 ^= row&7
    const int lin = (blockIdx.z * 2 + blockIdx.y) * 16 + blockIdx.x;  // hw linear id
    const int chunk = (lin & 7) * 128 + (lin >> 3);                   // XCD-chunked
    const int h = (chunk >> 5) & 15, b = chunk >> 9, mt = 31 - (chunk & 31);
    const int tid = threadIdx.x, w = tid >> 6, l64 = tid & 63;
    const int quad = l64 >> 4, ln = l64 & 15;

    // Q fragments (B-operand of S^T mfma): lane ln holds Q[q=ln][k=quad*8+i]
    f16x8 qf[4];
    {
        const int tq = mt * 64 + w * 16 + ln;
        const f16* qp = Q + (size_t)(b * 2048 + tq) * DMODEL + h * 128 + quad * 8;
#pragma unroll
        for (int kc = 0; kc < 4; ++kc) qf[kc] = *(const f16x8*)(qp + kc * 32);
    }
    f32x4 oacc[8];
#pragma unroll
    for (int ot = 0; ot < 8; ++ot)
#pragma unroll
        for (int r = 0; r < 4; ++r) oacc[ot][r] = 0.f;
    float m_r = -INFINITY, l_r = 0.f;  // per-lane: row q = ln

    const f16* kbase = K + (size_t)(b * 2048) * DMODEL + h * 128;
    const f16* vbase = Vt + (size_t)(b * 2048 + h * 128) * 2048;

    f16x8 kr[4], vr[4];
#pragma unroll
    for (int c = 0; c < 4; ++c) {
        int idx = c * 256 + tid;
        kr[c] = *(const f16x8*)(kbase + (size_t)(idx >> 4) * DMODEL + (idx & 15) * 8);
        vr[c] = *(const f16x8*)(vbase + (size_t)(idx >> 3) * 2048 + (idx & 7) * 8);
    }

    for (int j = 0; j <= mt; ++j) {
        __syncthreads();
#pragma unroll
        for (int c = 0; c < 4; ++c) {
            int idx = c * 256 + tid;
            int krow = idx >> 4, vrow = idx >> 3;
            *(f16x8*)&Kl[krow * 128 + (((idx & 15) ^ (krow & 7)) << 3)] = kr[c];
            *(f16x8*)&Vl[vrow * 64 + (((idx & 7) ^ (vrow & 7)) << 3)] = vr[c];
        }
        __syncthreads();
        if (j < mt) {
#pragma unroll
            for (int c = 0; c < 4; ++c) {
                int idx = c * 256 + tid;
                kr[c] = *(const f16x8*)(kbase + (size_t)((j + 1) * 64 + (idx >> 4)) * DMODEL + (idx & 15) * 8);
                vr[c] = *(const f16x8*)(vbase + (size_t)(idx >> 3) * 2048 + (j + 1) * 64 + (idx & 7) * 8);
            }
        }
        // S^T = K Q^T : A-frag = K rows (t_k), B-frag = Q. C: row=t_k(quad*4+r), col=q(ln)
        f32x4 sacc[4];
#pragma unroll
        for (int nt = 0; nt < 4; ++nt)
#pragma unroll
            for (int r = 0; r < 4; ++r) sacc[nt][r] = 0.f;
#pragma unroll
        for (int nt = 0; nt < 4; ++nt)
#pragma unroll
            for (int kc = 0; kc < 4; ++kc) {
                f16x8 kf = *(const f16x8*)&Kl[(nt * 16 + ln) * 128 + (((kc * 4 + quad) ^ (ln & 7)) << 3)];
                sacc[nt] = __builtin_amdgcn_mfma_f32_16x16x32_f16(kf, qf[kc], sacc[nt], 0, 0, 0);
            }
        if (j == mt) {  // diagonal: mask k > q
#pragma unroll
            for (int nt = 0; nt < 4; ++nt)
#pragma unroll
                for (int r = 0; r < 4; ++r)
                    if (nt * 16 + quad * 4 + r > w * 16 + ln) sacc[nt][r] = -INFINITY;
        }
        // online softmax: each lane owns its whole row (16 vals), reduce across quads only
        float mx = -INFINITY;
#pragma unroll
        for (int nt = 0; nt < 4; ++nt)
#pragma unroll
            for (int r = 0; r < 4; ++r) mx = fmaxf(mx, sacc[nt][r]);
        mx = fmaxf(mx, __shfl_xor(mx, 16));
        mx = fmaxf(mx, __shfl_xor(mx, 32));
        // T13 defer-max: only advance m when growth > 8 (P then bounded by e^8)
        const bool grow = (mx > m_r + 8.f);
        const float mn = grow ? fmaxf(m_r, mx) : m_r;
        const float alpha = grow ? __expf(m_r - mn) : 1.f;
        m_r = mn;
        f16x4 pa[4];
        float s0 = 0.f;
#pragma unroll
        for (int nt = 0; nt < 4; ++nt)
#pragma unroll
            for (int r = 0; r < 4; ++r) {
                float pv = __expf(sacc[nt][r] - mn);
                s0 += pv;
                pa[nt][r] = (f16)pv;
            }
        s0 += __shfl_xor(s0, 16);
        s0 += __shfl_xor(s0, 32);
        l_r = l_r * alpha + s0;
        // rescale O rows only if any lane's max grew (ballot is wave-uniform)
        if (__ballot(grow)) {
            float ar[4];
#pragma unroll
            for (int r = 0; r < 4; ++r) ar[r] = __shfl(alpha, (l64 & 48) | (quad * 4 + r));
#pragma unroll
            for (int ot = 0; ot < 8; ++ot)
#pragma unroll
                for (int r = 0; r < 4; ++r) oacc[ot][r] *= ar[r];
        }
        // O += P @ V via 16x16x16 (P already in A-layout in registers)
#pragma unroll
        for (int nt = 0; nt < 4; ++nt)
#pragma unroll
            for (int ot = 0; ot < 8; ++ot) {
                f16x4 vf = *(const f16x4*)&Vl[(ot * 16 + ln) * 64 + ((nt * 16 + quad * 4) ^ ((ln & 7) << 3))];
                oacc[ot] = __builtin_amdgcn_mfma_f32_16x16x16f16(pa[nt], vf, oacc[ot], 0, 0, 0);
            }
    }
    const float inv = 1.0f / l_r;
    float ivr[4];
#pragma unroll
    for (int r = 0; r < 4; ++r) ivr[r] = __shfl(inv, (l64 & 48) | (quad * 4 + r));
    __syncthreads();
#pragma unroll
    for (int ot = 0; ot < 8; ++ot)
#pragma unroll
        for (int r = 0; r < 4; ++r) {
            int row = w * 16 + quad * 4 + r;
            Kl[row * 128 + ((ot * 16 + ln) ^ ((row & 7) << 3))] = (f16)(oacc[ot][r] * ivr[r]);
        }
    __syncthreads();
#pragma unroll
    for (int c = 0; c < 4; ++c) {
        int idx = c * 256 + tid;
        int row = idx >> 4, col8 = idx & 15;
        *(f16x8*)&O[(size_t)(b * 2048 + mt * 64 + row) * DMODEL + h * 128 + col8 * 8] =
            *(const f16x8*)&Kl[row * 128 + ((col8 ^ (row & 7)) << 3)];
    }
}

// ----------------------------------------------------------------
extern "C" void kernel_launch(void* const* d_in, const int* in_sizes, int n_in,
                              void* d_out, int out_size, void* d_ws, size_t ws_size,
                              hipStream_t stream) {
    const float* x    = (const float*)d_in[0];
    const float* qaw  = (const float*)d_in[2];
    const float* qbw  = (const float*)d_in[3];
    const float* kvaw = (const float*)d_in[4];
    const float* kbw  = (const float*)d_in[5];
    const float* vbw  = (const float*)d_in[6];
    const float* ow   = (const float*)d_in[7];
    const float* qnw  = (const float*)d_in[8];
    const float* knw  = (const float*)d_in[9];
    float* out = (float*)d_out;

    char* p = (char*)d_ws;
    auto alloc = [&](size_t elems) { f16* r = (f16*)p; p += elems * sizeof(f16); return r; };
    f16* xb   = alloc((size_t)BT * 2048);     // reused as vt
    f16* wo   = alloc((size_t)2048 * 2048);
    f16* wqa  = alloc((size_t)1024 * 2048);   // attn overlay starts here
    f16* wqb  = alloc((size_t)2048 * 1024);
    f16* wkva = alloc((size_t)512 * 2048);
    f16* wkb  = alloc((size_t)2048 * 512);
    f16* wvb  = alloc((size_t)2048 * 512);
    f16* qlat = alloc((size_t)BT * 1024);
    f16* kvb  = alloc((size_t)BT * 512);
    f16* qpre = alloc((size_t)BT * 2048);
    f16* kpre = alloc((size_t)BT * 2048);
    f16* vt   = xb;    // [b][d][t], written by k_gemm8<2> after xb consumed
    f16* attn = wqa;   // overlays wqa..qlat, free post-GEMMs

    Cvt7 c;
    c.s[0] = x;    c.d[0] = xb;
    c.s[1] = qaw;  c.d[1] = wqa;
    c.s[2] = qbw;  c.d[2] = wqb;
    c.s[3] = kvaw; c.d[3] = wkva;
    c.s[4] = kbw;  c.d[4] = wkb;
    c.s[5] = vbw;  c.d[5] = wvb;
    c.s[6] = ow;   c.d[6] = wo;
    int sz4[7] = {BT * 2048 / 4, 1024 * 2048 / 4, 2048 * 1024 / 4, 512 * 2048 / 4,
                  2048 * 512 / 4, 2048 * 512 / 4, 2048 * 2048 / 4};
    c.off4[0] = 0;
    for (int i = 0; i < 7; ++i) c.off4[i + 1] = c.off4[i] + sz4[i];
    k_cvt7<<<(c.off4[7] + 255) / 256, 256, 0, stream>>>(c);

    // qlat = xb@wqa^T ; kvb = xb@wkva^T  (merged, split at col 1024)
    k_gemm8<1, f16><<<dim3(1536 / 256, BT / 128), 512, 0, stream>>>(
        xb, wqa, wkva, qlat, kvb, 2048, 1024, 1024, 512);
    // qpre = qlat@wqb^T
    k_gemm8<0, f16><<<dim3(2048 / 256, BT / 128), 512, 0, stream>>>(
        qlat, wqb, nullptr, qpre, nullptr, 1024, 0, 2048, 0);
    // kpre = kvb@wkb^T ; vt = transpose(kvb@wvb^T)  (merged, split at col 2048)
    k_gemm8<2, f16><<<dim3(4096 / 256, BT / 128), 512, 0, stream>>>(
        kvb, wkb, wvb, kpre, vt, 512, 0, 0, 0);
    // rmsnorm + rope in place
    k_norm_rope<<<32768, 256, 0, stream>>>(qpre, kpre, qnw, knw);
    // flash attention
    k_flash<<<dim3(16, 2, 32), 256, 0, stream>>>(qpre, kpre, vt, attn);
    // out = attn@wo^T (fp32)
    k_gemm8<0, float><<<dim3(2048 / 256, BT / 128), 512, 0, stream>>>(
        attn, wo, nullptr, out, nullptr, 2048, 0, 2048, 0);
}

// Round 6
// 381.484 us; speedup vs baseline: 1.2634x; 1.2634x over previous
//
#include <hip/hip_runtime.h>
#include <hip/hip_fp16.h>

typedef _Float16 f16;
typedef _Float16 f16x4 __attribute__((ext_vector_type(4)));
typedef _Float16 f16x8 __attribute__((ext_vector_type(8)));
typedef float f32x4 __attribute__((ext_vector_type(4)));

// B=2, T=2048, D=2048, NH=16, HD=128, Q_LAT=1024, KV_LAT=512
#define BT 4096
#define DMODEL 2048

__device__ __forceinline__ void gld16(const f16* g, f16* l) {
    __builtin_amdgcn_global_load_lds((const __attribute__((address_space(1))) void*)g,
                                     (__attribute__((address_space(3))) void*)l, 16, 0, 0);
}

// ---------------------------------------------------------------- fused fp32 -> fp16 (7 tensors, 1 launch)
struct Cvt7 {
    const float* s[7];
    f16* d[7];
    int off4[8];  // cumulative float4 counts
};
__global__ __launch_bounds__(256) void k_cvt7(Cvt7 c) {
    int i = blockIdx.x * 256 + threadIdx.x;
    if (i >= c.off4[7]) return;
    int seg = 0;
#pragma unroll
    for (int k = 1; k < 7; ++k) seg += (i >= c.off4[k]);
    int j = i - c.off4[seg];
    float4 v = ((const float4*)c.s[seg])[j];
    f16x4 h;
    h[0] = (f16)v.x; h[1] = (f16)v.y; h[2] = (f16)v.z; h[3] = (f16)v.w;
    ((f16x4*)c.d[seg])[j] = h;
}

// ---------------------------------------------------------------- pipelined GEMM (r3-proven loop)
// C[M,N] = A[M,K] @ B[N,K]^T. Tile 128(M) x 256(N), BK=64 as two 32-wide kc-halves.
// 512 threads = 8 waves (2M x 4N), per-wave 64x64 output. LDS 96KB -> 1 block/CU.
// XCD swizzle (kept from r5: measured neutral-to-positive, -6us): each XCD owns
// contiguous column-major chunks so its B-panels stay in one L2.
// MODE 0: plain -> C0 (CT). MODE 1: dual split at nsplit. MODE 2: k + V^T direct store.
template <int MODE, typename CT>
__global__ __launch_bounds__(512, 2) void k_gemm8(const f16* __restrict__ A,
                                                  const f16* __restrict__ B0,
                                                  const f16* __restrict__ B1,
                                                  CT* __restrict__ C0,
                                                  f16* __restrict__ C1,
                                                  int K, int nsplit, int ld0, int ld1) {
    __shared__ __align__(16) f16 lds[49152];  // 96 KB
    const int tid = threadIdx.x;
    const int w = tid >> 6, l = tid & 63;
    const int wm = w >> 2, wn = w & 3;          // 2M x 4N waves
    const int quad = l >> 4, ln = l & 15;
    const int gx = gridDim.x;
    const int lin = blockIdx.y * gx + blockIdx.x;
    const int nwg = gx << 5;                    // gridDim.y == 32
    const int chunk = (lin & 7) * (nwg >> 3) + (lin >> 3);
    const int m0 = (chunk & 31) * 128, n0 = (chunk >> 5) * 256;

    const f16* Bp;
    if constexpr (MODE == 0) {
        Bp = B0 + (size_t)n0 * K;
    } else if constexpr (MODE == 1) {
        Bp = (n0 < nsplit) ? B0 + (size_t)n0 * K : B1 + (size_t)(n0 - nsplit) * K;
    } else {
        Bp = (n0 < 2048) ? B0 + (size_t)n0 * K : B1 + (size_t)(n0 - 2048) * K;
    }

    // staging: A half = 128 rows x 32 k (1 round of 512x16B), B half = 256 x 32 (2 rounds)
    const f16* ag  = A + (size_t)(m0 + w * 16 + (l >> 2)) * K + (l & 3) * 8;
    const f16* bg0 = Bp + (size_t)(w * 16 + (l >> 2)) * K + (l & 3) * 8;
    const f16* bg1 = bg0 + (size_t)128 * K;
    f16* al = &lds[w * 512];         // + slot offset; lane*16B appended by HW
    f16* bl = &lds[4096 + w * 512];

#define STAGE8(buf_, kc_, t_)                          \
    {                                                  \
        const int off_ = ((buf_) * 2 + (kc_)) * 12288; \
        const int g_ = (t_) * 64 + (kc_) * 32;         \
        gld16(ag + g_, al + off_);                     \
        gld16(bg0 + g_, bl + off_);                    \
        gld16(bg1 + g_, bl + off_ + 4096);             \
    }

    f32x4 acc[4][4];
#pragma unroll
    for (int i = 0; i < 4; ++i)
#pragma unroll
        for (int j = 0; j < 4; ++j)
#pragma unroll
            for (int r = 0; r < 4; ++r) acc[i][j][r] = 0.f;

    const int nt = K >> 6;
    // prologue: tile 0 complete + tile 1 early half; vmcnt(3) -> tile 0 landed
    STAGE8(0, 0, 0);
    STAGE8(0, 1, 0);
    STAGE8(1, 0, 1);
    asm volatile("s_waitcnt vmcnt(3)" ::: "memory");
    __builtin_amdgcn_s_barrier();
    asm volatile("s_waitcnt lgkmcnt(0)" ::: "memory");

    for (int t = 0; t < nt; ++t) {
        const int buf = t & 1;
#pragma unroll
        for (int kc = 0; kc < 2; ++kc) {
            const f16* Ah = &lds[(buf * 2 + kc) * 12288];
            const f16* Bh = Ah + 4096;
            f16x8 a[4], b[4];
#pragma unroll
            for (int i = 0; i < 4; ++i)
                a[i] = *(const f16x8*)&Ah[(wm * 64 + i * 16 + ln) * 32 + quad * 8];
#pragma unroll
            for (int j = 0; j < 4; ++j)
                b[j] = *(const f16x8*)&Bh[(wn * 64 + j * 16 + ln) * 32 + quad * 8];
            if (kc == 0) {
                if (t + 1 < nt) STAGE8(buf ^ 1, 1, t + 1);  // late half of next tile
            } else {
                if (t + 2 < nt) STAGE8(buf, 0, t + 2);      // early half of tile+2 (kc0 just freed)
            }
            __builtin_amdgcn_s_barrier();
            asm volatile("s_waitcnt lgkmcnt(0)" ::: "memory");  // own frag reads done (compiler fence)
            __builtin_amdgcn_s_setprio(1);
#pragma unroll
            for (int i = 0; i < 4; ++i)
#pragma unroll
                for (int j = 0; j < 4; ++j)
                    acc[i][j] = __builtin_amdgcn_mfma_f32_16x16x32_f16(a[i], b[j], acc[i][j], 0, 0, 0);
            __builtin_amdgcn_s_setprio(0);
            if (kc == 1 && t + 1 < nt) {
                if (t + 2 < nt) asm volatile("s_waitcnt vmcnt(3)" ::: "memory");
                else            asm volatile("s_waitcnt vmcnt(0)" ::: "memory");
            }
            __builtin_amdgcn_s_barrier();
        }
    }
#undef STAGE8

    // ---------------- epilogue
    if constexpr (MODE == 2) {
        if (n0 >= 2048) {  // V^T: vt[(b*2048+d)*2048 + t], direct from acc (4 consecutive t per lane)
            const int d0 = n0 - 2048;
            const int bb = m0 >> 11, tb = m0 & 2047;
#pragma unroll
            for (int i = 0; i < 4; ++i)
#pragma unroll
                for (int j = 0; j < 4; ++j) {
                    f16x4 v;
#pragma unroll
                    for (int r = 0; r < 4; ++r) v[r] = (f16)acc[i][j][r];
                    *(f16x4*)&C1[((size_t)(bb * 2048 + d0 + wn * 64 + j * 16 + ln)) * 2048 +
                                 tb + wm * 64 + i * 16 + quad * 4] = v;
                }
            return;
        }
    }

    CT* Cd; int ldc; int cb;
    if constexpr (MODE == 0) {
        Cd = C0; ldc = ld0; cb = n0;
    } else if constexpr (MODE == 1) {
        if (n0 < nsplit) { Cd = C0; ldc = ld0; cb = n0; }
        else             { Cd = (CT*)C1; ldc = ld1; cb = n0 - nsplit; }
    } else {
        Cd = C0; ldc = 2048; cb = n0;
    }

    const int p = (wm ? 16 : 0) + quad * 4;
    if constexpr (sizeof(CT) == 2) {
        f16* Cs = (f16*)lds;  // [32][264]
#pragma unroll
        for (int i = 0; i < 4; ++i) {
            __syncthreads();
#pragma unroll
            for (int j = 0; j < 4; ++j)
#pragma unroll
                for (int r = 0; r < 4; ++r)
                    Cs[(p + r) * 264 + wn * 64 + j * 16 + ln] = (f16)acc[i][j][r];
            __syncthreads();
#pragma unroll
            for (int rr = 0; rr < 2; ++rr) {
                int idx = rr * 512 + tid;
                int row = idx >> 5, c8 = idx & 31;
                int rg = m0 + i * 16 + (row & 15) + ((row & 16) ? 64 : 0);
                *(f16x8*)&Cd[(size_t)rg * ldc + cb + c8 * 8] = *(const f16x8*)&Cs[row * 264 + c8 * 8];
            }
        }
    } else {
        float* Cs = (float*)lds;  // [32][260]
#pragma unroll
        for (int i = 0; i < 4; ++i) {
            __syncthreads();
#pragma unroll
            for (int j = 0; j < 4; ++j)
#pragma unroll
                for (int r = 0; r < 4; ++r)
                    Cs[(p + r) * 260 + wn * 64 + j * 16 + ln] = acc[i][j][r];
            __syncthreads();
#pragma unroll
            for (int rr = 0; rr < 4; ++rr) {
                int idx = rr * 512 + tid;
                int row = idx >> 6, c4 = idx & 63;
                int rg = m0 + i * 16 + (row & 15) + ((row & 16) ? 64 : 0);
                *(float4*)&Cd[(size_t)rg * ldc + cb + c4 * 4] = *(const float4*)&Cs[row * 260 + c4 * 4];
            }
        }
    }
}

// ---------------------------------------------------------------- RMSNorm + RoPE (in place)
__global__ __launch_bounds__(256) void k_norm_rope(f16* __restrict__ q, f16* __restrict__ k,
                                                   const float* __restrict__ qw,
                                                   const float* __restrict__ kw) {
    const int gw = blockIdx.x * 4 + (threadIdx.x >> 6);
    const int l = threadIdx.x & 63;
    const int which = gw >> 16;
    const int rh = gw & 65535;
    const int row = rh >> 4, h = rh & 15;
    f16* p = which ? k : q;
    const float* wp = which ? kw : qw;
    const float scale = which ? 1.0f : 0.08838834764831843f;  // 1/sqrt(128) folded into q
    const size_t base = (size_t)row * DMODEL + h * 128;
    float xa = (float)p[base + l];
    float xb = (float)p[base + 64 + l];
    float ss = xa * xa + xb * xb;
#pragma unroll
    for (int off = 32; off > 0; off >>= 1) ss += __shfl_xor(ss, off);
    const float rms = rsqrtf(ss * (1.0f / 128.0f) + 1e-6f);
    const float na = xa * rms * wp[l];
    const float nb = xb * rms * wp[64 + l];
    const int t = row & 2047;
    const float freq = __expf((float)l * -0.1439115683121279f);  // ln(10000)/64
    const float ang = (float)t * freq;
    const float c = cosf(ang), s = sinf(ang);
    p[base + l]      = (f16)((na * c - nb * s) * scale);
    p[base + 64 + l] = (f16)((nb * c + na * s) * scale);
}

// ---------------------------------------------------------------- flash attention, causal, BM=64 BN=64
// r4 version verbatim (89us, 84 VGPR, no spill). r5's (256,5) occupancy push REFUTED:
// register cap 102 < ~170 needed -> 50MB/dispatch scratch spill, 2x slowdown.
// S^T trick: S^T = K·Q^T so P lands in-register in 16x16x16 A-operand layout.
// grid (h, b, mtidx) = (16, 2, 32); mt = 31 - blockIdx.z (heavy first, (h,b) XCD-local).
// T13 defer-max: skip O-rescale when no lane's row-max grew by >8 (P bounded by e^8, f16-safe).
__global__ __launch_bounds__(256, 3) void k_flash(const f16* __restrict__ Q, const f16* __restrict__ K,
                                                  const f16* __restrict__ Vt, f16* __restrict__ O) {
    __shared__ f16 Kl[64 * 136];   // [t_k][d]
    __shared__ f16 Vl[128 * 72];   // [d][t_k]
    const int h = blockIdx.x, b = blockIdx.y, mt = 31 - blockIdx.z;
    const int tid = threadIdx.x, w = tid >> 6, l64 = tid & 63;
    const int quad = l64 >> 4, ln = l64 & 15;

    // Q fragments (B-operand of S^T mfma): lane ln holds Q[q=ln][k=quad*8+i]
    f16x8 qf[4];
    {
        const int tq = mt * 64 + w * 16 + ln;
        const f16* qp = Q + (size_t)(b * 2048 + tq) * DMODEL + h * 128 + quad * 8;
#pragma unroll
        for (int kc = 0; kc < 4; ++kc) qf[kc] = *(const f16x8*)(qp + kc * 32);
    }
    f32x4 oacc[8];
#pragma unroll
    for (int ot = 0; ot < 8; ++ot)
#pragma unroll
        for (int r = 0; r < 4; ++r) oacc[ot][r] = 0.f;
    float m_r = -INFINITY, l_r = 0.f;  // per-lane: row q = ln

    const f16* kbase = K + (size_t)(b * 2048) * DMODEL + h * 128;
    const f16* vbase = Vt + (size_t)(b * 2048 + h * 128) * 2048;

    f16x8 kr[4], vr[4];
#pragma unroll
    for (int c = 0; c < 4; ++c) {
        int idx = c * 256 + tid;
        kr[c] = *(const f16x8*)(kbase + (size_t)(idx >> 4) * DMODEL + (idx & 15) * 8);
        vr[c] = *(const f16x8*)(vbase + (size_t)(idx >> 3) * 2048 + (idx & 7) * 8);
    }

    for (int j = 0; j <= mt; ++j) {
        __syncthreads();
#pragma unroll
        for (int c = 0; c < 4; ++c) {
            int idx = c * 256 + tid;
            *(f16x8*)&Kl[(idx >> 4) * 136 + (idx & 15) * 8] = kr[c];
            *(f16x8*)&Vl[(idx >> 3) * 72 + (idx & 7) * 8] = vr[c];
        }
        __syncthreads();
        if (j < mt) {
#pragma unroll
            for (int c = 0; c < 4; ++c) {
                int idx = c * 256 + tid;
                kr[c] = *(const f16x8*)(kbase + (size_t)((j + 1) * 64 + (idx >> 4)) * DMODEL + (idx & 15) * 8);
                vr[c] = *(const f16x8*)(vbase + (size_t)(idx >> 3) * 2048 + (j + 1) * 64 + (idx & 7) * 8);
            }
        }
        // S^T = K Q^T : A-frag = K rows (t_k), B-frag = Q. C: row=t_k(quad*4+r), col=q(ln)
        f32x4 sacc[4];
#pragma unroll
        for (int nt = 0; nt < 4; ++nt)
#pragma unroll
            for (int r = 0; r < 4; ++r) sacc[nt][r] = 0.f;
#pragma unroll
        for (int nt = 0; nt < 4; ++nt)
#pragma unroll
            for (int kc = 0; kc < 4; ++kc) {
                f16x8 kf = *(const f16x8*)&Kl[(nt * 16 + ln) * 136 + kc * 32 + quad * 8];
                sacc[nt] = __builtin_amdgcn_mfma_f32_16x16x32_f16(kf, qf[kc], sacc[nt], 0, 0, 0);
            }
        if (j == mt) {  // diagonal: mask k > q
#pragma unroll
            for (int nt = 0; nt < 4; ++nt)
#pragma unroll
                for (int r = 0; r < 4; ++r)
                    if (nt * 16 + quad * 4 + r > w * 16 + ln) sacc[nt][r] = -INFINITY;
        }
        // online softmax: each lane owns its whole row (16 vals), reduce across quads only
        float mx = -INFINITY;
#pragma unroll
        for (int nt = 0; nt < 4; ++nt)
#pragma unroll
            for (int r = 0; r < 4; ++r) mx = fmaxf(mx, sacc[nt][r]);
        mx = fmaxf(mx, __shfl_xor(mx, 16));
        mx = fmaxf(mx, __shfl_xor(mx, 32));
        // T13 defer-max: only advance m when growth > 8 (P then bounded by e^8)
        const bool grow = (mx > m_r + 8.f);
        const float mn = grow ? fmaxf(m_r, mx) : m_r;
        const float alpha = grow ? __expf(m_r - mn) : 1.f;
        m_r = mn;
        f16x4 pa[4];
        float s0 = 0.f;
#pragma unroll
        for (int nt = 0; nt < 4; ++nt)
#pragma unroll
            for (int r = 0; r < 4; ++r) {
                float pv = __expf(sacc[nt][r] - mn);
                s0 += pv;
                pa[nt][r] = (f16)pv;
            }
        s0 += __shfl_xor(s0, 16);
        s0 += __shfl_xor(s0, 32);
        l_r = l_r * alpha + s0;
        // rescale O rows only if any lane's max grew (ballot is wave-uniform)
        if (__ballot(grow)) {
            float ar[4];
#pragma unroll
            for (int r = 0; r < 4; ++r) ar[r] = __shfl(alpha, (l64 & 48) | (quad * 4 + r));
#pragma unroll
            for (int ot = 0; ot < 8; ++ot)
#pragma unroll
                for (int r = 0; r < 4; ++r) oacc[ot][r] *= ar[r];
        }
        // O += P @ V via 16x16x16 (P already in A-layout in registers)
#pragma unroll
        for (int nt = 0; nt < 4; ++nt)
#pragma unroll
            for (int ot = 0; ot < 8; ++ot) {
                f16x4 vf = *(const f16x4*)&Vl[(ot * 16 + ln) * 72 + nt * 16 + quad * 4];
                oacc[ot] = __builtin_amdgcn_mfma_f32_16x16x16f16(pa[nt], vf, oacc[ot], 0, 0, 0);
            }
    }
    const float inv = 1.0f / l_r;
    float ivr[4];
#pragma unroll
    for (int r = 0; r < 4; ++r) ivr[r] = __shfl(inv, (l64 & 48) | (quad * 4 + r));
    __syncthreads();
#pragma unroll
    for (int ot = 0; ot < 8; ++ot)
#pragma unroll
        for (int r = 0; r < 4; ++r)
            Kl[(w * 16 + quad * 4 + r) * 136 + ot * 16 + ln] = (f16)(oacc[ot][r] * ivr[r]);
    __syncthreads();
#pragma unroll
    for (int c = 0; c < 4; ++c) {
        int idx = c * 256 + tid;
        int row = idx >> 4, col8 = (idx & 15) * 8;
        *(f16x8*)&O[(size_t)(b * 2048 + mt * 64 + row) * DMODEL + h * 128 + col8] =
            *(const f16x8*)&Kl[row * 136 + col8];
    }
}

// ----------------------------------------------------------------
extern "C" void kernel_launch(void* const* d_in, const int* in_sizes, int n_in,
                              void* d_out, int out_size, void* d_ws, size_t ws_size,
                              hipStream_t stream) {
    const float* x    = (const float*)d_in[0];
    const float* qaw  = (const float*)d_in[2];
    const float* qbw  = (const float*)d_in[3];
    const float* kvaw = (const float*)d_in[4];
    const float* kbw  = (const float*)d_in[5];
    const float* vbw  = (const float*)d_in[6];
    const float* ow   = (const float*)d_in[7];
    const float* qnw  = (const float*)d_in[8];
    const float* knw  = (const float*)d_in[9];
    float* out = (float*)d_out;

    char* p = (char*)d_ws;
    auto alloc = [&](size_t elems) { f16* r = (f16*)p; p += elems * sizeof(f16); return r; };
    f16* xb   = alloc((size_t)BT * 2048);     // reused as vt
    f16* wo   = alloc((size_t)2048 * 2048);
    f16* wqa  = alloc((size_t)1024 * 2048);   // attn overlay starts here
    f16* wqb  = alloc((size_t)2048 * 1024);
    f16* wkva = alloc((size_t)512 * 2048);
    f16* wkb  = alloc((size_t)2048 * 512);
    f16* wvb  = alloc((size_t)2048 * 512);
    f16* qlat = alloc((size_t)BT * 1024);
    f16* kvb  = alloc((size_t)BT * 512);
    f16* qpre = alloc((size_t)BT * 2048);
    f16* kpre = alloc((size_t)BT * 2048);
    f16* vt   = xb;    // [b][d][t], written by k_gemm8<2> after xb consumed
    f16* attn = wqa;   // overlays wqa..qlat, free post-GEMMs

    Cvt7 c;
    c.s[0] = x;    c.d[0] = xb;
    c.s[1] = qaw;  c.d[1] = wqa;
    c.s[2] = qbw;  c.d[2] = wqb;
    c.s[3] = kvaw; c.d[3] = wkva;
    c.s[4] = kbw;  c.d[4] = wkb;
    c.s[5] = vbw;  c.d[5] = wvb;
    c.s[6] = ow;   c.d[6] = wo;
    int sz4[7] = {BT * 2048 / 4, 1024 * 2048 / 4, 2048 * 1024 / 4, 512 * 2048 / 4,
                  2048 * 512 / 4, 2048 * 512 / 4, 2048 * 2048 / 4};
    c.off4[0] = 0;
    for (int i = 0; i < 7; ++i) c.off4[i + 1] = c.off4[i] + sz4[i];
    k_cvt7<<<(c.off4[7] + 255) / 256, 256, 0, stream>>>(c);

    // qlat = xb@wqa^T ; kvb = xb@wkva^T  (merged, split at col 1024)
    k_gemm8<1, f16><<<dim3(1536 / 256, BT / 128), 512, 0, stream>>>(
        xb, wqa, wkva, qlat, kvb, 2048, 1024, 1024, 512);
    // qpre = qlat@wqb^T
    k_gemm8<0, f16><<<dim3(2048 / 256, BT / 128), 512, 0, stream>>>(
        qlat, wqb, nullptr, qpre, nullptr, 1024, 0, 2048, 0);
    // kpre = kvb@wkb^T ; vt = transpose(kvb@wvb^T)  (merged, split at col 2048)
    k_gemm8<2, f16><<<dim3(4096 / 256, BT / 128), 512, 0, stream>>>(
        kvb, wkb, wvb, kpre, vt, 512, 0, 0, 0);
    // rmsnorm + rope in place
    k_norm_rope<<<32768, 256, 0, stream>>>(qpre, kpre, qnw, knw);
    // flash attention
    k_flash<<<dim3(16, 2, 32), 256, 0, stream>>>(qpre, kpre, vt, attn);
    // out = attn@wo^T (fp32)
    k_gemm8<0, float><<<dim3(2048 / 256, BT / 128), 512, 0, stream>>>(
        attn, wo, nullptr, out, nullptr, 2048, 0, 2048, 0);
}